// Round 1
// baseline (378.714 us; speedup 1.0000x reference)
//
#include <hip/hip_runtime.h>

typedef unsigned int u32;
typedef unsigned short u16;
typedef short short8 __attribute__((ext_vector_type(8)));
typedef float f32x4 __attribute__((ext_vector_type(4)));

#define R_ 32
#define KEYS_PER_B 2048   // 32 relations * 64 nodes per batch
#define SSTAGE 1536       // staged sorted-edge slots per block (avg 767, ~27 sigma headroom)
#define AGG_STRIDE 136    // bf16 elems; 272B row = 16B aligned, 2-way banks (free)

static __device__ __forceinline__ u16 f2bf(float f) {
  u32 u = __float_as_uint(f);
  u = (u + 0x7FFFu + ((u >> 16) & 1u)) >> 16;   // RNE
  return (u16)u;
}
static __device__ __forceinline__ float bf2f(u16 v) {
  return __uint_as_float(((u32)v) << 16);
}

// ---- x fp32 -> bf16 ----
__global__ void k_convert_x(const float* __restrict__ x, u16* __restrict__ xb, int n4) {
  int i = blockIdx.x * 256 + threadIdx.x;
  if (i >= n4) return;
  const float4 f = ((const float4*)x)[i];
  u32 lo = (u32)f2bf(f.x) | ((u32)f2bf(f.y) << 16);
  u32 hi = (u32)f2bf(f.z) | ((u32)f2bf(f.w) << 16);
  ((uint2*)xb)[i] = make_uint2(lo, hi);
}

// ---- pack W (and W_root as slot 32) into MFMA B-fragment order ----
// wp[(((r*8 + ct)*4 + ks)*64 + lane)*8 + j] = W[r][ks*32 + (lane>>4)*8 + j][ct*16 + (lane&15)]
__global__ void k_pack_w(const float* __restrict__ W, const float* __restrict__ Wroot,
                         u16* __restrict__ wp, u16* __restrict__ wrootp) {
  int tid = blockIdx.x * 256 + threadIdx.x;
  if (tid >= 33 * 2048) return;
  int lane = tid & 63;
  int ks = (tid >> 6) & 3;
  int ct = (tid >> 8) & 7;
  int rr = tid >> 11;
  int i0 = ks * 32 + (lane >> 4) * 8;
  int o  = ct * 16 + (lane & 15);
  const float* src = (rr < 32) ? (W + (size_t)rr * (128 * 128)) : Wroot;
  u16* dst = (rr < 32) ? (wp + ((size_t)((rr * 8 + ct) * 4 + ks) * 64 + lane) * 8)
                       : (wrootp + ((size_t)((ct * 4 + ks) * 64 + lane)) * 8);
#pragma unroll
  for (int j = 0; j < 8; ++j) dst[j] = f2bf(src[(size_t)(i0 + j) * 128 + o]);
}

// ---- histogram of sort keys ----
__global__ void k_hist(const int* __restrict__ ei, const int* __restrict__ et,
                       int* __restrict__ hist, int E) {
  int e = blockIdx.x * 256 + threadIdx.x;
  if (e >= E) return;
  int tgt = ei[E + e];
  int r = et[e];
  int key = (tgt >> 6) * KEYS_PER_B + r * 64 + (tgt & 63);
  atomicAdd(hist + key, 1);
}

// ---- per-chunk exclusive scan (chunk = 2048 keys = one batch) ----
__global__ __launch_bounds__(256) void k_scan_local(const int* __restrict__ hist,
                                                    int* __restrict__ offs,
                                                    int* __restrict__ chunkSums) {
  __shared__ int wsum[4];
  int b = blockIdx.x, t = threadIdx.x;
  size_t base = (size_t)b * KEYS_PER_B + (size_t)t * 8;
  int4 a = *(const int4*)(hist + base);
  int4 c = *(const int4*)(hist + base + 4);
  int v[8] = {a.x, a.y, a.z, a.w, c.x, c.y, c.z, c.w};
  int s = 0;
#pragma unroll
  for (int i = 0; i < 8; ++i) s += v[i];
  int lane = t & 63, w = t >> 6;
  int x = s;
#pragma unroll
  for (int off = 1; off < 64; off <<= 1) {
    int y = __shfl_up(x, off);
    if (lane >= off) x += y;
  }
  if (lane == 63) wsum[w] = x;
  __syncthreads();
  int wb = 0;
  for (int i = 0; i < w; ++i) wb += wsum[i];
  int ex = wb + x - s;
  int o[8];
#pragma unroll
  for (int i = 0; i < 8; ++i) { o[i] = ex; ex += v[i]; }
  *(int4*)(offs + base) = make_int4(o[0], o[1], o[2], o[3]);
  *(int4*)(offs + base + 4) = make_int4(o[4], o[5], o[6], o[7]);
  if (t == 255) chunkSums[b] = wb + x;
}

// ---- scan of chunk sums (1 block, 1 wave) ----
__global__ void k_scan_chunks(const int* __restrict__ cs, int* __restrict__ cb, int n) {
  int l = threadIdx.x;
  int carry = 0;
  int iters = (n + 63) >> 6;
  for (int i = 0; i < iters; ++i) {
    int idx = i * 64 + l;
    int v = (idx < n) ? cs[idx] : 0;
    int x = v;
#pragma unroll
    for (int off = 1; off < 64; off <<= 1) {
      int y = __shfl_up(x, off);
      if (l >= off) x += y;
    }
    if (idx < n) cb[idx] = carry + x - v;
    carry += __shfl(x, 63);
  }
}

// ---- scatter to sorted order; offs[key] becomes per-key chunk-local END ----
__global__ void k_scatter(const int* __restrict__ ei, const int* __restrict__ et,
                          int* __restrict__ offs, const int* __restrict__ chunkBase,
                          u32* __restrict__ sorted, int E) {
  int e = blockIdx.x * 256 + threadIdx.x;
  if (e >= E) return;
  int src = ei[e];
  int tgt = ei[E + e];
  int r = et[e];
  int chunk = tgt >> 6;
  int key = chunk * KEYS_PER_B + r * 64 + (tgt & 63);
  int p = atomicAdd(offs + key, 1) + chunkBase[chunk];
  sorted[p] = (u32)src;
}

// ---- main batch kernel: per 64-node batch, 33 GEMMs (32 relations + root) ----
__global__ __launch_bounds__(256) void k_batch(
    const u16* __restrict__ xb, const u16* __restrict__ wp, const u16* __restrict__ wrootp,
    const float* __restrict__ bias, const u32* __restrict__ sorted,
    const int* __restrict__ offs, const int* __restrict__ hist,
    const int* __restrict__ chunkBase, float* __restrict__ h, int N) {
  __shared__ u16 aggb[64 * AGG_STRIDE];
  __shared__ u32 sStage[SSTAGE];
  const int b = blockIdx.x, t = threadIdx.x;
  const int lane = t & 63, w = t >> 6;
  const int m = lane & 15, q = lane >> 4;
  const int nb = b * 64;
  const int keyBase = b * KEYS_PER_B;
  const int cb = chunkBase[b];

  // stage this chunk's sorted edge srcs into LDS (chunk-local positions)
  const int nEdge = offs[keyBase + KEYS_PER_B - 1];
  for (int i = t; i < nEdge && i < SSTAGE; i += 256) sStage[i] = sorted[cb + i];

  const short8 zero8 = {0, 0, 0, 0, 0, 0, 0, 0};
  f32x4 acc[4][2];
#pragma unroll
  for (int rt = 0; rt < 4; ++rt)
#pragma unroll
    for (int c = 0; c < 2; ++c) acc[rt][c] = (f32x4){0.f, 0.f, 0.f, 0.f};

  const int wct0 = w * 2;  // this wave owns col-tiles wct0, wct0+1 (cols w*32..w*32+31)

  // ---- root GEMM: acc += x_batch @ W_root ----
#pragma unroll
  for (int ks = 0; ks < 4; ++ks) {
    const int kb = ks * 32 + q * 8;
    short8 af[4];
#pragma unroll
    for (int rt = 0; rt < 4; ++rt) {
      int node = nb + rt * 16 + m;
      af[rt] = (node < N) ? *(const short8*)(xb + (size_t)node * 128 + kb) : zero8;
    }
#pragma unroll
    for (int c = 0; c < 2; ++c) {
      short8 bf = *(const short8*)(wrootp + ((size_t)(((wct0 + c) * 4 + ks) * 64 + lane)) * 8);
#pragma unroll
      for (int rt = 0; rt < 4; ++rt)
        acc[rt][c] = __builtin_amdgcn_mfma_f32_16x16x32_bf16(af[rt], bf, acc[rt][c], 0, 0, 0);
    }
  }
  __syncthreads();  // sStage ready

  // ---- relation loop ----
  for (int r = 0; r < R_; ++r) {
    const int k0 = keyBase + r * 64;
    // per-lane preload of the wave's 16 keys' (cnt, end) — broadcast later via shfl
    const int myKey = k0 + w * 16 + (lane & 15);
    const int cntv = hist[myKey];
    const int endv = offs[myKey];
    const int segStart = offs[k0] - hist[k0];
    const int segEnd = offs[k0 + 63];
    if (segEnd > segStart) {  // uniform across block
      // aggregation: wave w owns rows w*16 .. w*16+15 (register-accumulate, no atomics)
      for (int kk = 0; kk < 16; ++kk) {
        const int cnt = __shfl(cntv, kk);
        const int enL = __shfl(endv, kk);
        float v0 = 0.f, v1 = 0.f;
        if (cnt > 0) {
          for (int p = enL - cnt; p < enL; ++p) {
            const u32 srcn = (p < SSTAGE) ? sStage[p] : sorted[cb + p];
            const u32 xv = *(const u32*)(xb + (size_t)srcn * 128 + lane * 2);
            v0 += bf2f((u16)(xv & 0xFFFFu));
            v1 += bf2f((u16)(xv >> 16));
          }
          const float sc = 1.f / (float)cnt;   // mean norm (cnt >= 1 here)
          v0 *= sc; v1 *= sc;
        }
        const int tl = w * 16 + kk;
        *(u32*)(aggb + (size_t)tl * AGG_STRIDE + lane * 2) =
            (u32)f2bf(v0) | ((u32)f2bf(v1) << 16);
      }
      __syncthreads();
      // GEMM: acc += agg @ W[r]
#pragma unroll
      for (int ks = 0; ks < 4; ++ks) {
        const int kb = ks * 32 + q * 8;
        short8 af[4];
#pragma unroll
        for (int rt = 0; rt < 4; ++rt)
          af[rt] = *(const short8*)(aggb + (size_t)(rt * 16 + m) * AGG_STRIDE + kb);
#pragma unroll
        for (int c = 0; c < 2; ++c) {
          short8 bf = *(const short8*)(wp + ((size_t)(((r * 8 + wct0 + c) * 4 + ks) * 64 + lane)) * 8);
#pragma unroll
          for (int rt = 0; rt < 4; ++rt)
            acc[rt][c] = __builtin_amdgcn_mfma_f32_16x16x32_bf16(af[rt], bf, acc[rt][c], 0, 0, 0);
        }
      }
      __syncthreads();  // before next relation overwrites aggb
    }
  }

  // ---- epilogue: bias + relu + store h (fp32) ----
#pragma unroll
  for (int c = 0; c < 2; ++c) {
    const int col = (wct0 + c) * 16 + m;
    const float bv = bias[col];
#pragma unroll
    for (int rt = 0; rt < 4; ++rt) {
#pragma unroll
      for (int g = 0; g < 4; ++g) {
        const int row = nb + rt * 16 + q * 4 + g;  // D layout: col=lane&15, row=q*4+reg
        if (row < N) {
          float v = acc[rt][c][g] + bv;
          h[(size_t)row * 128 + col] = v > 0.f ? v : 0.f;
        }
      }
    }
  }
}

// ---- DistMult scoring: one wave per triplet ----
__global__ void k_score(const float* __restrict__ h, const float* __restrict__ rel_emb,
                        const int* __restrict__ head, const int* __restrict__ tail,
                        const int* __restrict__ rel, float* __restrict__ out, int T) {
  int lane = threadIdx.x & 63, w = threadIdx.x >> 6;
  int gid = blockIdx.x * 4 + w;
  if (gid >= T) return;
  const float* ph = h + (size_t)head[gid] * 128;
  const float* pt = h + (size_t)tail[gid] * 128;
  const float* pr = rel_emb + (size_t)rel[gid] * 128;
  float s = ph[lane] * pr[lane] * pt[lane] + ph[lane + 64] * pr[lane + 64] * pt[lane + 64];
#pragma unroll
  for (int off = 32; off > 0; off >>= 1) s += __shfl_down(s, off);
  if (lane == 0) out[gid] = s;
}

extern "C" void kernel_launch(void* const* d_in, const int* in_sizes, int n_in,
                              void* d_out, int out_size, void* d_ws, size_t ws_size,
                              hipStream_t stream) {
  const float* x     = (const float*)d_in[0];
  const float* W     = (const float*)d_in[1];
  const float* Wroot = (const float*)d_in[2];
  const float* bias  = (const float*)d_in[3];
  const float* relE  = (const float*)d_in[4];
  const int* ei      = (const int*)d_in[5];
  const int* et      = (const int*)d_in[6];
  const int* headI   = (const int*)d_in[7];
  const int* tailI   = (const int*)d_in[8];
  const int* relI    = (const int*)d_in[9];
  float* out = (float*)d_out;

  const int N = in_sizes[0] / 128;   // 50000
  const int E = in_sizes[6];         // 600000
  const int T = in_sizes[7];         // 8192
  const int NB = (N + 63) >> 6;      // 782
  const int NKEYS = NB * KEYS_PER_B;

  char* p = (char*)d_ws;
  auto alloc = [&](size_t bytes) -> void* {
    void* r = (void*)p;
    p += (bytes + 255) & ~(size_t)255;
    return r;
  };
  u16* xb     = (u16*)alloc((size_t)N * 128 * 2);        // 12.8 MB
  u16* wp     = (u16*)alloc((size_t)32 * 2048 * 8 * 2);  // 1 MB
  u16* wrootp = (u16*)alloc((size_t)2048 * 8 * 2);       // 32 KB
  int* hist   = (int*)alloc((size_t)NKEYS * 4);          // 6.4 MB
  int* offs   = (int*)alloc((size_t)NKEYS * 4);          // 6.4 MB
  int* csum   = (int*)alloc((size_t)NB * 4);
  int* cbase  = (int*)alloc((size_t)NB * 4);
  u32* sorted = (u32*)alloc((size_t)E * 4);              // 2.4 MB
  float* h    = (float*)alloc((size_t)N * 128 * 4);      // 25.6 MB

  hipMemsetAsync(hist, 0, (size_t)NKEYS * 4, stream);
  k_convert_x<<<(N * 128 / 4 + 255) / 256, 256, 0, stream>>>(x, xb, N * 128 / 4);
  k_pack_w<<<(33 * 2048 + 255) / 256, 256, 0, stream>>>(W, Wroot, wp, wrootp);
  k_hist<<<(E + 255) / 256, 256, 0, stream>>>(ei, et, hist, E);
  k_scan_local<<<NB, 256, 0, stream>>>(hist, offs, csum);
  k_scan_chunks<<<1, 64, 0, stream>>>(csum, cbase, NB);
  k_scatter<<<(E + 255) / 256, 256, 0, stream>>>(ei, et, offs, cbase, sorted, E);
  k_batch<<<NB, 256, 0, stream>>>(xb, wp, wrootp, bias, sorted, offs, hist, cbase, h, N);
  k_score<<<(T + 3) / 4, 256, 0, stream>>>(h, relE, headI, tailI, relI, out, T);
}